// Round 12
// baseline (1204.294 us; speedup 1.0000x reference)
//
#include <hip/hip_runtime.h>

#define H 1024
#define FH 4096
#define T 32
#define HSZ (1u << 20)   // u16 elements per h buffer (2 MB)

typedef unsigned short u16;
typedef unsigned int u32;
typedef __attribute__((ext_vector_type(8))) short short8;
typedef __attribute__((ext_vector_type(4))) float f32x4;
typedef __attribute__((ext_vector_type(4))) u32 u32x4;

__device__ __forceinline__ u16 f2b(float f) {
    union { float f; u32 i; } x; x.f = f;
    u32 r = x.i + 0x7fff + ((x.i >> 16) & 1);
    return (u16)(r >> 16);
}
__device__ __forceinline__ float sigm(float x) {
    return __fdividef(1.f, 1.f + __expf(-x));
}
__device__ __forceinline__ float ftanh(float x) {
    float t = __expf(-2.f * fabsf(x));
    return copysignf(__fdividef(1.f - t, 1.f + t), x);
}

// ---------- prep: W_eff = W_hh + W_ih⊗W_out, bf16, row-major [4096][1024] ----------
__global__ void prep_weff_k(const float* __restrict__ Whh, const float* __restrict__ Wih,
                            const float* __restrict__ Wo, u16* __restrict__ weff) {
    int idx = (blockIdx.x * 256 + threadIdx.x) * 8;   // grid 2048
    int r = idx >> 10, k = idx & 1023;
    float wih = Wih[r];
    short8 outv;
#pragma unroll
    for (int e = 0; e < 8; e++) {
        float v = Whh[idx + e] + wih * Wo[k + e];
        outv[e] = (short)f2b(v);
    }
    *(short8*)(weff + idx) = outv;
}

// ---------- prep: h0->bf16 (buf0, row-major), bias', out = b_out ----------
__global__ void prep_misc_k(const float* __restrict__ h0, const float* __restrict__ bih,
                            const float* __restrict__ bhh, const float* __restrict__ bo,
                            const float* __restrict__ Wih,
                            u16* __restrict__ hbase, float* __restrict__ biasp,
                            float* __restrict__ out) {
    int i = (blockIdx.x * 256 + threadIdx.x) * 4;     // grid 1024
#pragma unroll
    for (int e = 0; e < 4; e++) hbase[i + e] = f2b(h0[i + e]);
    if (blockIdx.x == 0) {
        for (int b = threadIdx.x; b < FH; b += 256)
            biasp[b] = bih[b] + bhh[b] + bo[0] * Wih[b];
    }
    if (blockIdx.x < 32) {
        float b0 = bo[0];
        int o = blockIdx.x * 1024 + threadIdx.x * 4;
#pragma unroll
        for (int e = 0; e < 4; e++) out[o + e] = b0;
    }
}

// ---------- prep: d0 = in_data - (h0 . Wout + b_out) ----------
__global__ void prep_d0_k(const float* __restrict__ in_data, const float* __restrict__ h0,
                          const float* __restrict__ Wo, const float* __restrict__ bo,
                          float* __restrict__ dd0) {
    int lane = threadIdx.x & 63, wid = threadIdx.x >> 6;   // grid 64 x 256
    for (int rr = 0; rr < 4; ++rr) {
        int m = blockIdx.x * 16 + (wid << 2) + rr;
        const float* hp = h0 + ((u32)m << 10) + lane * 16;
        const float* wp = Wo + lane * 16;
        float s = 0.f;
#pragma unroll
        for (int e = 0; e < 16; e++) s += hp[e] * wp[e];
#pragma unroll
        for (int off = 32; off >= 1; off >>= 1) s += __shfl_xor(s, off, 64);
        if (lane == 0) dd0[m] = in_data[m] - s - bo[0];
    }
}

// ---------- persistent: 32 steps; 128x128 tile; 8 waves = 2 K-halves x (2x2) of 64x64 ----------
// R10 schedule (dbuf K-loop: 1 barrier/it; single-pass 128KB epilogue) with TWO changes:
//   (1) GLOBAL 256-block step barrier (not per-mb): aligns all mb-groups in time so
//       same-XCD cross-group weff reads hit L2 (R10's drift killed dedup -> 1.24GB FETCH)
//   (2) B(0) staged in the step prologue (no under-spin prefetch; confound removed)
template<bool COH>
__global__ __launch_bounds__(512) void lstm_persist_k(
    const u16* __restrict__ weff, u16* __restrict__ hbase,
    const float* __restrict__ biasp, const float* __restrict__ dd0,
    const float* __restrict__ Wih, const float* __restrict__ Wo,
    const float* __restrict__ c0, float* __restrict__ out, u32* __restrict__ cnt)
{
    __shared__ __align__(16) char smem[131072];  // buf0 [0,64K) buf1 [64K,128K); gb overlays

    const int tid = threadIdx.x;
    const int lane = tid & 63, wid = tid >> 6;
    const int kg = wid >> 2;                     // K-half: 0 -> [0,512), 1 -> [512,1024)
    const int wrr = (wid >> 1) & 1, wcc = wid & 1;  // 2x2 grid of 64x64 wave tiles
    const int bx = blockIdx.x;
    const int mb = (bx >> 3) & 7;                // 8 row-groups of 128
    const int jb = (bx & 7) * 4 + (bx >> 6);     // 32 j-slices of 32, XCD-clustered
    const int m0 = mb << 7, j0 = jb << 5;
    const int rl = lane & 15, sl = lane >> 4;
    const int jj = tid & 31, rgrp = tid >> 5;    // epilogue: 16 groups x 8 rows
    const int j = j0 + jj;

    const float bs0 = biasp[j], bs1 = biasp[H + j], bs2 = biasp[2*H + j], bs3 = biasp[3*H + j];
    const float wi0 = Wih[j], wi1 = Wih[H + j], wi2 = Wih[2*H + j], wi3 = Wih[3*H + j];
    const float woj = Wo[j];
    float c_reg[8];
#pragma unroll
    for (int q = 0; q < 8; ++q)
        c_reg[q] = c0[(u32)(m0 + rgrp * 8 + q) * H + j];

    // staging descriptors: tile = 128 rows x 128 k-elems (64 per K-half);
    // LDS slot (row, cs) holds source k-chunk (cs ^ (row&15)) -> swizzled read below.
    int arow[4], brow[4], koff[4], dstA[4], dstB[4];
#pragma unroll
    for (int i = 0; i < 4; i++) {
        int c_ = tid + i * 512;
        int row = c_ >> 4, cs = c_ & 15;
        koff[i] = (cs >> 3) * 512 + (cs & 7) * 8;           // k-elem offset (K-half + chunk)
        arow[i] = m0 + row;
        brow[i] = ((row >> 5) << 10) + j0 + (row & 31);     // gate-group row of weff
        int dchunk = row * 16 + (cs ^ (row & 15));          // dest-side XOR swizzle
        dstA[i] = dchunk * 16;
        dstB[i] = 32768 + dchunk * 16;
    }

    for (int s = 0; s < T; ++s) {
        const u16* hin = hbase + (u32)(COH ? (s & 1) : s) * HSZ;
        u16* hout      = hbase + (u32)(COH ? ((s + 1) & 1) : (s + 1)) * HSZ;

        f32x4 acc[4][4];
#pragma unroll
        for (int im = 0; im < 4; im++)
#pragma unroll
            for (int in_ = 0; in_ < 4; in_++) acc[im][in_] = (f32x4){0.f, 0.f, 0.f, 0.f};

        u32x4 ph[4], pw[4];
        auto loadA = [&](int it) {
#pragma unroll
            for (int i = 0; i < 4; i++) {
                const u16* pa = hin + ((u32)arow[i] << 10) + it * 64 + koff[i];
                if constexpr (COH) {
                    asm volatile("global_load_dwordx4 %0, %1, off sc0 sc1"
                                 : "=v"(ph[i]) : "v"(pa));
                } else {
                    ph[i] = *(const u32x4*)pa;
                }
            }
        };
        auto loadB = [&](int it) {
#pragma unroll
            for (int i = 0; i < 4; i++)
                pw[i] = *(const u32x4*)(weff + ((u32)brow[i] << 10) + it * 64 + koff[i]);
        };
        auto writeA = [&](int buf) {
            if constexpr (COH) {
                asm volatile("s_waitcnt vmcnt(0)" ::: "memory");
                __builtin_amdgcn_sched_barrier(0);
            }
#pragma unroll
            for (int i = 0; i < 4; i++) *(u32x4*)(smem + buf * 65536 + dstA[i]) = ph[i];
        };
        auto writeB = [&](int buf) {
#pragma unroll
            for (int i = 0; i < 4; i++) *(u32x4*)(smem + buf * 65536 + dstB[i]) = pw[i];
        };

        // prologue: stage tile 0 into buf0 (A and B both)
        loadA(0); loadB(0);
        writeA(0); writeB(0);

        for (int it = 0; it < 8; ++it) {
            const int buf = it & 1;
            __syncthreads();                       // buf `buf` fully staged & visible
            if (it < 7) { loadA(it + 1); loadB(it + 1); }
            const char* base = smem + buf * 65536;
            __builtin_amdgcn_s_setprio(1);
#pragma unroll
            for (int ks = 0; ks < 2; ++ks) {
                short8 af[4], bg[4];
#pragma unroll
                for (int im = 0; im < 4; ++im) {
                    int row = wrr * 64 + im * 16 + rl;
                    int sb = row * 256 + (((kg * 8 + ks * 4 + sl) * 16) ^ ((row & 15) << 4));
                    af[im] = *(const short8*)(base + sb);
                }
#pragma unroll
                for (int in_ = 0; in_ < 4; ++in_) {
                    int n = wcc * 64 + in_ * 16 + rl;
                    int sb = 32768 + n * 256 + (((kg * 8 + ks * 4 + sl) * 16) ^ ((n & 15) << 4));
                    bg[in_] = *(const short8*)(base + sb);
                }
#pragma unroll
                for (int im = 0; im < 4; ++im)
#pragma unroll
                    for (int in_ = 0; in_ < 4; ++in_)
                        acc[im][in_] = __builtin_amdgcn_mfma_f32_16x16x32_bf16(
                            af[im], bg[in_], acc[im][in_], 0, 0, 0);
            }
            __builtin_amdgcn_s_setprio(0);
            if (it < 7) { writeA(buf ^ 1); writeB(buf ^ 1); }  // write-late into other buf
        }

        // ---------- single-pass epilogue: gb[wrr][kg] = [64][128] f32 each ----------
        __syncthreads();                           // all staging/compute done; LDS all dead
        {
            float* g = (float*)(smem + wrr * 65536 + kg * 32768);
#pragma unroll
            for (int im = 0; im < 4; ++im)
#pragma unroll
                for (int in_ = 0; in_ < 4; ++in_)
#pragma unroll
                    for (int qq = 0; qq < 4; ++qq) {
                        int r = im * 16 + sl * 4 + qq;
                        int col = wcc * 64 + in_ * 16 + rl;
                        g[r * 128 + (col ^ ((r & 7) << 2))] = acc[im][in_][qq];
                    }
        }
        __syncthreads();
#pragma unroll
        for (int q = 0; q < 8; ++q) {
            int m_loc = rgrp * 8 + q;
            int m_abs = m0 + m_loc;
            const float* g0 = (const float*)(smem + (m_loc >> 6) * 65536);
            const float* g1 = g0 + 8192;           // kg=1 partial (+32768 B)
            int r = m_loc & 63;
            int jx = jj ^ ((r & 7) << 2);
            const float* r0 = g0 + r * 128;
            const float* r1 = g1 + r * 128;
            float gi  = r0[jx]      + r1[jx]      + bs0;
            float gf_ = r0[32 + jx] + r1[32 + jx] + bs1;
            float gg_ = r0[64 + jx] + r1[64 + jx] + bs2;
            float go_ = r0[96 + jx] + r1[96 + jx] + bs3;
            if (s == 0) {
                float d = dd0[m_abs];
                gi += d * wi0; gf_ += d * wi1; gg_ += d * wi2; go_ += d * wi3;
            }
            float cn = sigm(gf_) * c_reg[q] + sigm(gi) * ftanh(gg_);
            float hn = sigm(go_) * ftanh(cn);
            c_reg[q] = cn;

            if (s < T - 1) {
                u32 hv = (u32)f2b(hn);
                u32 nb = __shfl_down(hv, 1, 32);
                if (!(jj & 1)) {
                    u32* hp = (u32*)(hout + (((u32)m_abs << 10) + j));
                    __hip_atomic_store(hp, (nb << 16) | hv,
                                       __ATOMIC_RELAXED, __HIP_MEMORY_SCOPE_AGENT);
                }
            }
            float yp = hn * woj;
            yp += __shfl_xor(yp, 16, 32);
            yp += __shfl_xor(yp, 8, 32);
            yp += __shfl_xor(yp, 4, 32);
            yp += __shfl_xor(yp, 2, 32);
            yp += __shfl_xor(yp, 1, 32);
            if (jj == 0)
                __hip_atomic_fetch_add(out + (u32)m_abs * T + s, yp,
                                       __ATOMIC_RELAXED, __HIP_MEMORY_SCOPE_AGENT);
        }

        // ---------- GLOBAL step barrier: all 256 blocks (cross-group alignment clock) ----------
        if (s < T - 1) {
            __syncthreads();   // h stores drained (implicit vmcnt(0)) before arrival
            u32* cc = cnt + ((u32)s << 4);         // 64B-spaced counter per step
            if (tid == 0) {
                __hip_atomic_fetch_add(cc, 1u, __ATOMIC_RELAXED, __HIP_MEMORY_SCOPE_AGENT);
                while (__hip_atomic_load(cc, __ATOMIC_RELAXED, __HIP_MEMORY_SCOPE_AGENT) < 256u)
                    __builtin_amdgcn_s_sleep(2);
            }
            __syncthreads();
        }
    }
}

extern "C" void kernel_launch(void* const* d_in, const int* in_sizes, int n_in,
                              void* d_out, int out_size, void* d_ws, size_t ws_size,
                              hipStream_t stream) {
    const float* in_data = (const float*)d_in[0];
    // d_in[1] = batch_size (int scalar), unused
    const float* h0  = (const float*)d_in[2];
    const float* c0  = (const float*)d_in[3];
    const float* Wih = (const float*)d_in[4];
    const float* Whh = (const float*)d_in[5];
    const float* bih = (const float*)d_in[6];
    const float* bhh = (const float*)d_in[7];
    const float* Wo  = (const float*)d_in[8];
    const float* bo  = (const float*)d_in[9];
    float* out = (float*)d_out;
    char* ws = (char*)d_ws;

    u16*   weff  = (u16*)ws;                            // 8 MB  W_eff bf16 row-major
    float* biasp = (float*)(ws + (8u << 20));           // 16 KB bias'
    float* dd0   = (float*)(ws + (8u << 20) + 16384);   // 4 KB  step-0 correction
    u32*   cnt   = (u32*)(ws + (8u << 20) + 24576);     // 16 KB barrier counters
    u16*   hbase = (u16*)(ws + (8u << 20) + 65536);     // 2 MB x (33 rot / 2 coh)

    bool rot = ws_size >= ((size_t)76 << 20);

    hipMemsetAsync(cnt, 0, 16384, stream);
    hipLaunchKernelGGL(prep_weff_k, dim3(2048), dim3(256), 0, stream, Whh, Wih, Wo, weff);
    hipLaunchKernelGGL(prep_misc_k, dim3(1024), dim3(256), 0, stream,
                       h0, bih, bhh, bo, Wih, hbase, biasp, out);
    hipLaunchKernelGGL(prep_d0_k, dim3(64), dim3(256), 0, stream, in_data, h0, Wo, bo, dd0);

    if (rot)
        hipLaunchKernelGGL((lstm_persist_k<false>), dim3(256), dim3(512), 0, stream,
                           weff, hbase, biasp, dd0, Wih, Wo, c0, out, cnt);
    else
        hipLaunchKernelGGL((lstm_persist_k<true>), dim3(256), dim3(512), 0, stream,
                           weff, hbase, biasp, dd0, Wih, Wo, c0, out, cnt);
}

// Round 14
// 509.901 us; speedup vs baseline: 2.3618x; 2.3618x over previous
//
#include <hip/hip_runtime.h>

#define H 1024
#define FH 4096
#define T 32
#define HSZ (1u << 20)   // u16 elements per h buffer (2 MB)

typedef unsigned short u16;
typedef unsigned int u32;
typedef __attribute__((ext_vector_type(8))) short short8;
typedef __attribute__((ext_vector_type(4))) float f32x4;
typedef __attribute__((ext_vector_type(4))) u32 u32x4;

__device__ __forceinline__ u16 f2b(float f) {
    union { float f; u32 i; } x; x.f = f;
    u32 r = x.i + 0x7fff + ((x.i >> 16) & 1);
    return (u16)(r >> 16);
}
__device__ __forceinline__ float sigm(float x) {
    return __fdividef(1.f, 1.f + __expf(-x));
}
__device__ __forceinline__ float ftanh(float x) {
    float t = __expf(-2.f * fabsf(x));
    return copysignf(__fdividef(1.f - t, 1.f + t), x);
}

// ---------- prep: W_eff = W_hh + W_ih⊗W_out, bf16, FRAGMENT-MAJOR ----------
// frag f = gct*32 + kstep (gct 0..255 = gate-row/16, kstep 0..31 = k/32)
// lane l, elem e: gate-row r = gct*16 + (l&15), k = kstep*32 + (l>>4)*8 + e
// -> each b-frag load in the GEMM is one coalesced 1KB global load.
__global__ void prep_weff_k(const float* __restrict__ Whh, const float* __restrict__ Wih,
                            const float* __restrict__ Wo, u16* __restrict__ wf) {
    int t = blockIdx.x * 256 + threadIdx.x;   // grid 2048 -> 524288 = 8192 frags x 64 lanes
    int f = t >> 6, l = t & 63;
    int gct = f >> 5, kstep = f & 31;
    int r = gct * 16 + (l & 15);
    int k0 = kstep * 32 + (l >> 4) * 8;
    float wih = Wih[r];
    const float* wr_ = Whh + (u32)r * H + k0;
    const float* wo_ = Wo + k0;
    short8 v;
#pragma unroll
    for (int e = 0; e < 8; e++) v[e] = (short)f2b(wr_[e] + wih * wo_[e]);
    *(short8*)(wf + ((u32)f << 9) + l * 8) = v;
}

// ---------- prep: h0->bf16 (buf0, row-major), bias', out = b_out ----------
__global__ void prep_misc_k(const float* __restrict__ h0, const float* __restrict__ bih,
                            const float* __restrict__ bhh, const float* __restrict__ bo,
                            const float* __restrict__ Wih,
                            u16* __restrict__ hbase, float* __restrict__ biasp,
                            float* __restrict__ out) {
    int i = (blockIdx.x * 256 + threadIdx.x) * 4;     // grid 1024
#pragma unroll
    for (int e = 0; e < 4; e++) hbase[i + e] = f2b(h0[i + e]);
    if (blockIdx.x == 0) {
        for (int b = threadIdx.x; b < FH; b += 256)
            biasp[b] = bih[b] + bhh[b] + bo[0] * Wih[b];
    }
    if (blockIdx.x < 32) {
        float b0 = bo[0];
        int o = blockIdx.x * 1024 + threadIdx.x * 4;
#pragma unroll
        for (int e = 0; e < 4; e++) out[o + e] = b0;
    }
}

// ---------- prep: d0 = in_data - (h0 . Wout + b_out) ----------
__global__ void prep_d0_k(const float* __restrict__ in_data, const float* __restrict__ h0,
                          const float* __restrict__ Wo, const float* __restrict__ bo,
                          float* __restrict__ dd0) {
    int lane = threadIdx.x & 63, wid = threadIdx.x >> 6;   // grid 64 x 256
    for (int rr = 0; rr < 4; ++rr) {
        int m = blockIdx.x * 16 + (wid << 2) + rr;
        const float* hp = h0 + ((u32)m << 10) + lane * 16;
        const float* wp = Wo + lane * 16;
        float s = 0.f;
#pragma unroll
        for (int e = 0; e < 16; e++) s += hp[e] * wp[e];
#pragma unroll
        for (int off = 32; off >= 1; off >>= 1) s += __shfl_xor(s, off, 64);
        if (lane == 0) dd0[m] = in_data[m] - s - bo[0];
    }
}

// ---------- persistent: 32 steps; 128x128 tile; 8 waves = 2 K-halves x (2x2) of 64x64 ----------
// R9 skeleton (proven 511us, FETCH 268 MB) with ONE structural change:
//   B (weff) no longer staged through LDS — step-invariant, loaded per-iteration as
//   fragment-major coalesced 1KB global loads (L2-resident slice, barrier-paced bursts).
//   A staging, barrier cadence (2/it), block mapping, epilogue: byte-identical to R9.
template<bool COH>
__global__ __launch_bounds__(512) void lstm_persist_k(
    const u16* __restrict__ wf, u16* __restrict__ hbase,
    const float* __restrict__ biasp, const float* __restrict__ dd0,
    const float* __restrict__ Wih, const float* __restrict__ Wo,
    const float* __restrict__ c0, float* __restrict__ out, u32* __restrict__ cnt)
{
    // stage A [0,32K); epilogue gb0 [0,33792) gb1 [33792,67584) overlay
    __shared__ __align__(16) char smem[67584];
    float* gb0 = (float*)smem;
    float* gb1 = (float*)(smem + 33792);

    const int tid = threadIdx.x;
    const int lane = tid & 63, wid = tid >> 6;
    const int kg = wid >> 2;                     // K-half: 0 -> [0,512), 1 -> [512,1024)
    const int wrr = (wid >> 1) & 1, wcc = wid & 1;  // 2x2 grid of 64x64 wave tiles
    const int bx = blockIdx.x;
    const int mb = (bx >> 3) & 7;                // 8 row-groups of 128
    const int jb = (bx & 7) * 4 + (bx >> 6);     // 32 j-slices of 32, XCD-clustered
    const int m0 = mb << 7, j0 = jb << 5;
    const int rl = lane & 15, sl = lane >> 4;
    const int jj = tid & 31, rgrp = tid >> 5;    // epilogue: 16 row-groups x 32 j
    const int j = j0 + jj;

    const float bs0 = biasp[j], bs1 = biasp[H + j], bs2 = biasp[2*H + j], bs3 = biasp[3*H + j];
    const float wi0 = Wih[j], wi1 = Wih[H + j], wi2 = Wih[2*H + j], wi3 = Wih[3*H + j];
    const float woj = Wo[j];
    float c_reg[8];
#pragma unroll
    for (int p = 0; p < 2; ++p)
#pragma unroll
        for (int q = 0; q < 4; ++q)
            c_reg[p * 4 + q] = c0[(u32)(m0 + p * 64 + rgrp * 4 + q) * H + j];

    // A staging descriptors: tile = 128 rows x 128 k (64 per K-half), 2048 16B-chunks,
    // 4 per thread. LDS slot (row,cs) holds source chunk (cs ^ (row&15)).
    int arow[4], koff[4], dstA[4];
#pragma unroll
    for (int i = 0; i < 4; i++) {
        int c_ = tid + i * 512;
        int row = c_ >> 4, cs = c_ & 15;
        koff[i] = (cs >> 3) * 512 + (cs & 7) * 8;           // k-elem offset (K-half + chunk)
        arow[i] = m0 + row;
        dstA[i] = (row * 16 + (cs ^ (row & 15))) * 16;      // dest-side XOR swizzle
    }

    // b-frag gct per n-tile: block col-tile = wcc*4+in_ -> gate g, 16-col sub
    int gct[4];
#pragma unroll
    for (int in_ = 0; in_ < 4; ++in_) {
        int ctb = wcc * 4 + in_;
        gct[in_] = (ctb >> 1) * 64 + jb * 2 + (ctb & 1);
    }

    for (int s = 0; s < T; ++s) {
        const u16* hin = hbase + (u32)(COH ? (s & 1) : s) * HSZ;
        u16* hout      = hbase + (u32)(COH ? ((s + 1) & 1) : (s + 1)) * HSZ;

        f32x4 acc[4][4];
#pragma unroll
        for (int im = 0; im < 4; im++)
#pragma unroll
            for (int in_ = 0; in_ < 4; in_++) acc[im][in_] = (f32x4){0.f, 0.f, 0.f, 0.f};

        u32x4 ph[4];
        auto loadA = [&](int it) {
#pragma unroll
            for (int i = 0; i < 4; i++) {
                const u16* pa = hin + ((u32)arow[i] << 10) + it * 64 + koff[i];
                if constexpr (COH) {
                    asm volatile("global_load_dwordx4 %0, %1, off sc0 sc1"
                                 : "=v"(ph[i]) : "v"(pa));
                } else {
                    ph[i] = *(const u32x4*)pa;
                }
            }
        };
        auto writeA = [&]() {
            if constexpr (COH) {
                asm volatile("s_waitcnt vmcnt(0)" ::: "memory");
                __builtin_amdgcn_sched_barrier(0);
            }
#pragma unroll
            for (int i = 0; i < 4; i++) *(u32x4*)(smem + dstA[i]) = ph[i];
        };

        loadA(0); writeA();

        for (int it = 0; it < 8; ++it) {
            __syncthreads();                       // A tile `it` visible
            // B burst: 8 coalesced 1KB frag loads from L2-resident weff slice
            short8 bg[2][4];
#pragma unroll
            for (int ks = 0; ks < 2; ++ks)
#pragma unroll
                for (int in_ = 0; in_ < 4; ++in_) {
                    u32 fidx = (u32)(gct[in_] * 32 + kg * 16 + it * 2 + ks);
                    bg[ks][in_] = *(const short8*)(wf + (fidx << 9) + lane * 8);
                }
            if (it < 7) loadA(it + 1);             // next A tile in flight under compute
#pragma unroll
            for (int ks = 0; ks < 2; ++ks) {
                short8 af[4];
#pragma unroll
                for (int im = 0; im < 4; ++im) {
                    int row = wrr * 64 + im * 16 + rl;
                    int sb = row * 256 + (((kg * 8 + ks * 4 + sl) * 16) ^ ((row & 15) << 4));
                    af[im] = *(const short8*)(smem + sb);
                }
#pragma unroll
                for (int im = 0; im < 4; ++im)
#pragma unroll
                    for (int in_ = 0; in_ < 4; ++in_)
                        acc[im][in_] = __builtin_amdgcn_mfma_f32_16x16x32_bf16(
                            af[im], bg[ks][in_], acc[im][in_], 0, 0, 0);
            }
            __syncthreads();                       // compute on tile it done
            if (it < 7) writeA();                  // overwrite A buffer with tile it+1
        }

        // ---------- epilogue: 2 row-passes; kg partials summed via gb0+gb1 ----------
#pragma unroll
        for (int p = 0; p < 2; ++p) {
            __syncthreads();
            if (wrr == p) {
                float* g = kg ? gb1 : gb0;
#pragma unroll
                for (int im = 0; im < 4; ++im)
#pragma unroll
                    for (int in_ = 0; in_ < 4; ++in_)
#pragma unroll
                        for (int qq = 0; qq < 4; ++qq) {
                            int r = im * 16 + sl * 4 + qq;
                            g[r * 132 + wcc * 64 + in_ * 16 + rl] = acc[im][in_][qq];
                        }
            }
            __syncthreads();
#pragma unroll
            for (int q = 0; q < 4; ++q) {
                int rloc = rgrp * 4 + q;
                int m_abs = m0 + p * 64 + rloc;
                const float* g0 = gb0 + rloc * 132;
                const float* g1 = gb1 + rloc * 132;
                float gi  = g0[jj]      + g1[jj]      + bs0;
                float gf_ = g0[32 + jj] + g1[32 + jj] + bs1;
                float gg_ = g0[64 + jj] + g1[64 + jj] + bs2;
                float go_ = g0[96 + jj] + g1[96 + jj] + bs3;
                if (s == 0) {
                    float d = dd0[m_abs];
                    gi += d * wi0; gf_ += d * wi1; gg_ += d * wi2; go_ += d * wi3;
                }
                float cn = sigm(gf_) * c_reg[p * 4 + q] + sigm(gi) * ftanh(gg_);
                float hn = sigm(go_) * ftanh(cn);
                c_reg[p * 4 + q] = cn;

                if (s < T - 1) {
                    u32 hv = (u32)f2b(hn);
                    u32 nb = __shfl_down(hv, 1, 32);
                    if (!(jj & 1)) {
                        u32* hp = (u32*)(hout + (((u32)m_abs << 10) + j));
                        __hip_atomic_store(hp, (nb << 16) | hv,
                                           __ATOMIC_RELAXED, __HIP_MEMORY_SCOPE_AGENT);
                    }
                }
                float yp = hn * woj;
                yp += __shfl_xor(yp, 16, 32);
                yp += __shfl_xor(yp, 8, 32);
                yp += __shfl_xor(yp, 4, 32);
                yp += __shfl_xor(yp, 2, 32);
                yp += __shfl_xor(yp, 1, 32);
                if (jj == 0)
                    __hip_atomic_fetch_add(out + (u32)m_abs * T + s, yp,
                                           __ATOMIC_RELAXED, __HIP_MEMORY_SCOPE_AGENT);
            }
        }

        // ---------- group barrier: 32 blocks sharing mb ----------
        if (s < T - 1) {
            __syncthreads();   // drains vmcnt -> h stores visible at coherence point
            if (tid == 0) {
                u32* cc = cnt + ((u32)(s * 8 + mb) << 4);
                __hip_atomic_fetch_add(cc, 1u, __ATOMIC_RELAXED, __HIP_MEMORY_SCOPE_AGENT);
                while (__hip_atomic_load(cc, __ATOMIC_RELAXED, __HIP_MEMORY_SCOPE_AGENT) < 32u)
                    __builtin_amdgcn_s_sleep(2);
            }
            __syncthreads();
        }
    }
}

extern "C" void kernel_launch(void* const* d_in, const int* in_sizes, int n_in,
                              void* d_out, int out_size, void* d_ws, size_t ws_size,
                              hipStream_t stream) {
    const float* in_data = (const float*)d_in[0];
    // d_in[1] = batch_size (int scalar), unused
    const float* h0  = (const float*)d_in[2];
    const float* c0  = (const float*)d_in[3];
    const float* Wih = (const float*)d_in[4];
    const float* Whh = (const float*)d_in[5];
    const float* bih = (const float*)d_in[6];
    const float* bhh = (const float*)d_in[7];
    const float* Wo  = (const float*)d_in[8];
    const float* bo  = (const float*)d_in[9];
    float* out = (float*)d_out;
    char* ws = (char*)d_ws;

    u16*   weff  = (u16*)ws;                            // 8 MB  W_eff bf16 frag-major
    float* biasp = (float*)(ws + (8u << 20));           // 16 KB bias'
    float* dd0   = (float*)(ws + (8u << 20) + 16384);   // 4 KB  step-0 correction
    u32*   cnt   = (u32*)(ws + (8u << 20) + 24576);     // 16 KB barrier counters
    u16*   hbase = (u16*)(ws + (8u << 20) + 65536);     // 2 MB x (33 rot / 2 coh)

    bool rot = ws_size >= ((size_t)76 << 20);

    hipMemsetAsync(cnt, 0, 16384, stream);
    hipLaunchKernelGGL(prep_weff_k, dim3(2048), dim3(256), 0, stream, Whh, Wih, Wo, weff);
    hipLaunchKernelGGL(prep_misc_k, dim3(1024), dim3(256), 0, stream,
                       h0, bih, bhh, bo, Wih, hbase, biasp, out);
    hipLaunchKernelGGL(prep_d0_k, dim3(64), dim3(256), 0, stream, in_data, h0, Wo, bo, dd0);

    if (rot)
        hipLaunchKernelGGL((lstm_persist_k<false>), dim3(256), dim3(512), 0, stream,
                           weff, hbase, biasp, dd0, Wih, Wo, c0, out, cnt);
    else
        hipLaunchKernelGGL((lstm_persist_k<true>), dim3(256), dim3(512), 0, stream,
                           weff, hbase, biasp, dd0, Wih, Wo, c0, out, cnt);
}